// Round 1
// baseline (5692.671 us; speedup 1.0000x reference)
//
#include <hip/hip_runtime.h>
#include <math.h>

#define NN 50000
#define FINN 64
#define HD 128
#define EE 800000
#define TT 8
#define PP 250000
#define DD 500000
#define GG 20000
#define VV 2000
#define OO 2

// ------------------------------------------------------------------
// utility: histogram counts for CSR build
__global__ void count_k(const int* __restrict__ idx, int* __restrict__ counts, int n) {
    int i = blockIdx.x * blockDim.x + threadIdx.x;
    if (i < n) atomicAdd(&counts[idx[i]], 1);
}

// single-block chunked exclusive scan; rowptr has n+1 entries
__global__ void scan_excl_k(const int* __restrict__ counts, int* __restrict__ rowptr, int n) {
    __shared__ int buf[1024];
    __shared__ int carry_s;
    int tid = threadIdx.x;
    if (tid == 0) carry_s = 0;
    __syncthreads();
    for (int base = 0; base < n; base += 1024) {
        int i = base + tid;
        int v = (i < n) ? counts[i] : 0;
        buf[tid] = v;
        __syncthreads();
        for (int off = 1; off < 1024; off <<= 1) {
            int t = (tid >= off) ? buf[tid - off] : 0;
            __syncthreads();
            buf[tid] += t;
            __syncthreads();
        }
        int incl = buf[tid];
        int carry = carry_s;
        if (i < n) rowptr[i] = carry + incl - v;
        __syncthreads();                 // everyone read carry_s before update
        if (tid == 1023) carry_s = carry + buf[1023];
        __syncthreads();
    }
    if (tid == 0) rowptr[n] = carry_s;
}

__global__ void fill_csr_k(const int* __restrict__ esrc, const int* __restrict__ edst,
                           const int* __restrict__ rowptr, int* __restrict__ cursor,
                           int* __restrict__ outi, int n) {
    int e = blockIdx.x * blockDim.x + threadIdx.x;
    if (e < n) {
        int d = edst[e];
        int pos = atomicAdd(&cursor[d], 1);
        outi[rowptr[d] + pos] = esrc[e];
    }
}

// ------------------------------------------------------------------
// mean-aggregation: one block per node, one thread per feature
__global__ void agg_k(const float* __restrict__ h, const int* __restrict__ rowptr,
                      const int* __restrict__ csr_src, float* __restrict__ agg, int Kin) {
    int node = blockIdx.x;
    int j = threadIdx.x;
    int s = rowptr[node], e = rowptr[node + 1];
    float sum = 0.f;
    for (int i = s; i < e; ++i) {
        int src = csr_src[i];
        sum += h[(long)src * Kin + j];
    }
    float d = fmaxf((float)(e - s), 1.f);
    agg[(long)node * Kin + j] = sum / d;
}

// ------------------------------------------------------------------
// h_out = relu([hin | agg] @ [Ws ; Wn] + b)   tile: 64 rows x 128 cols
__launch_bounds__(256)
__global__ void mp_gemm_k(const float* __restrict__ hin, const float* __restrict__ agg,
                          const float* __restrict__ Ws, const float* __restrict__ Wn,
                          const float* __restrict__ bias, float* __restrict__ hout, int Kin) {
    __shared__ float At[32][65];                   // [kk][row]
    __shared__ __align__(16) float Bt[32][128];    // [kk][col]
    int tid = threadIdx.x;
    int tx = tid & 31;       // col group: cols tx*4..tx*4+3
    int ty = tid >> 5;       // row phase: rows ty + 8*i
    int row0 = blockIdx.x * 64;
    float acc[8][4] = {};
    int K = 2 * Kin;
    for (int k0 = 0; k0 < K; k0 += 32) {
        for (int l = tid; l < 64 * 32; l += 256) {
            int r = l >> 5, kk = l & 31;
            int grow = row0 + r;
            int k = k0 + kk;
            float v = 0.f;
            if (grow < NN)
                v = (k < Kin) ? hin[(long)grow * Kin + k] : agg[(long)grow * Kin + (k - Kin)];
            At[kk][r] = v;
        }
        for (int l = tid; l < 32 * 128; l += 256) {
            int kk = l >> 7, c = l & 127;
            int k = k0 + kk;
            Bt[kk][c] = (k < Kin) ? Ws[k * HD + c] : Wn[(k - Kin) * HD + c];
        }
        __syncthreads();
#pragma unroll
        for (int kk = 0; kk < 32; ++kk) {
            float4 b = *(const float4*)&Bt[kk][tx * 4];
#pragma unroll
            for (int i = 0; i < 8; ++i) {
                float a = At[kk][ty + 8 * i];
                acc[i][0] += a * b.x;
                acc[i][1] += a * b.y;
                acc[i][2] += a * b.z;
                acc[i][3] += a * b.w;
            }
        }
        __syncthreads();
    }
    float4 bv = *(const float4*)&bias[tx * 4];
#pragma unroll
    for (int i = 0; i < 8; ++i) {
        int grow = row0 + ty + 8 * i;
        if (grow < NN) {
            float4 o;
            o.x = fmaxf(acc[i][0] + bv.x, 0.f);
            o.y = fmaxf(acc[i][1] + bv.y, 0.f);
            o.z = fmaxf(acc[i][2] + bv.z, 0.f);
            o.w = fmaxf(acc[i][3] + bv.w, 0.f);
            *(float4*)&hout[(long)grow * HD + tx * 4] = o;
        }
    }
}

// ------------------------------------------------------------------
// fused decoder: gather cat(32x384) -> GEMM vs Wd1 -> relu -> Wd2 -> log_softmax
__launch_bounds__(256)
__global__ void decoder_k(const float* __restrict__ feats, const int* __restrict__ place_idx,
                          const int* __restrict__ src_idx, const int* __restrict__ t_idx,
                          const int* __restrict__ dst_nodes, const int* __restrict__ dst_rowptr,
                          const float* __restrict__ Wd1, const float* __restrict__ bd1,
                          const float* __restrict__ Wd2, const float* __restrict__ bd2,
                          float* __restrict__ logprob) {
    __shared__ float cat[32][385];
    __shared__ __align__(16) float Wt[8][384];
    __shared__ float lred[32][2];
    int tid = threadIdx.x;
    int p0 = blockIdx.x * 32;

    // gather place & src features
    for (int l = tid; l < 32 * 128; l += 256) {
        int r = l >> 7, c = l & 127;
        int p = p0 + r;
        float pv = 0.f, sv = 0.f;
        if (p < PP) {
            long t = t_idx[p];
            pv = feats[(t * NN + place_idx[p]) * HD + c];
            sv = feats[(t * NN + src_idx[p]) * HD + c];
        }
        cat[r][c] = pv;
        cat[r][128 + c] = sv;
    }
    // dst segment-sum feature
    for (int l = tid; l < 32 * 128; l += 256) {
        int r = l >> 7, c = l & 127;
        int p = p0 + r;
        float s = 0.f;
        if (p < PP) {
            long t = t_idx[p];
            int js = dst_rowptr[p], je = dst_rowptr[p + 1];
            for (int j = js; j < je; ++j)
                s += feats[(t * NN + dst_nodes[j]) * HD + c];
        }
        cat[r][256 + c] = s;
    }

    int cx = tid & 31;   // 12 cols: cx*12 .. cx*12+11
    int ry = tid >> 5;   // 4 rows: ry*4 .. ry*4+3
    float acc[4][12];
#pragma unroll
    for (int i = 0; i < 4; ++i)
#pragma unroll
        for (int j = 0; j < 12; ++j) acc[i][j] = 0.f;

    for (int k0 = 0; k0 < 384; k0 += 8) {
        __syncthreads();     // previous tile consumed (and, first iter, cat written)
        for (int l = tid; l < 8 * 384; l += 256) {
            int kk = l / 384, c = l - kk * 384;
            Wt[kk][c] = Wd1[(k0 + kk) * 384 + c];
        }
        __syncthreads();
#pragma unroll
        for (int kk = 0; kk < 8; ++kk) {
            float a0 = cat[ry * 4 + 0][k0 + kk];
            float a1 = cat[ry * 4 + 1][k0 + kk];
            float a2 = cat[ry * 4 + 2][k0 + kk];
            float a3 = cat[ry * 4 + 3][k0 + kk];
            float wv[12];
            const float4* wr = (const float4*)&Wt[kk][cx * 12];
            *(float4*)&wv[0] = wr[0];
            *(float4*)&wv[4] = wr[1];
            *(float4*)&wv[8] = wr[2];
#pragma unroll
            for (int j = 0; j < 12; ++j) {
                acc[0][j] += a0 * wv[j];
                acc[1][j] += a1 * wv[j];
                acc[2][j] += a2 * wv[j];
                acc[3][j] += a3 * wv[j];
            }
        }
    }

    // bias + relu + Wd2 partial logits
    float part[4][2] = {};
#pragma unroll
    for (int j = 0; j < 12; ++j) {
        int c = cx * 12 + j;
        float b = bd1[c];
        float w0 = Wd2[c * 2 + 0], w1 = Wd2[c * 2 + 1];
#pragma unroll
        for (int i = 0; i < 4; ++i) {
            float h = fmaxf(acc[i][j] + b, 0.f);
            part[i][0] += h * w0;
            part[i][1] += h * w1;
        }
    }
    __syncthreads();
    if (tid < 64) ((float*)lred)[tid] = 0.f;
    __syncthreads();
#pragma unroll
    for (int i = 0; i < 4; ++i) {
        atomicAdd(&lred[ry * 4 + i][0], part[i][0]);
        atomicAdd(&lred[ry * 4 + i][1], part[i][1]);
    }
    __syncthreads();
    if (tid < 32) {
        int p = p0 + tid;
        if (p < PP) {
            float l0 = lred[tid][0] + bd2[0];
            float l1 = lred[tid][1] + bd2[1];
            float m = fmaxf(l0, l1);
            float lse = m + logf(expf(l0 - m) + expf(l1 - m));
            logprob[p * 2 + 0] = l0 - lse;
            logprob[p * 2 + 1] = l1 - lse;
        }
    }
}

// ------------------------------------------------------------------
__global__ void group_sum_k(const float* __restrict__ logprob, const int* __restrict__ group_id,
                            float* __restrict__ group_sums) {
    int p = blockIdx.x * blockDim.x + threadIdx.x;
    if (p >= PP) return;
    int g = group_id[p];
    atomicAdd(&group_sums[g * 2 + 0], logprob[p * 2 + 0]);
    atomicAdd(&group_sums[g * 2 + 1], logprob[p * 2 + 1]);
}

// segmented inclusive cumsum within each variant's contiguous group range
__global__ void within_k(const float* __restrict__ group_sums, const int* __restrict__ var_rowptr,
                         float* __restrict__ within) {
    int v = blockIdx.x * blockDim.x + threadIdx.x;
    if (v >= VV) return;
    int gs = var_rowptr[v], ge = var_rowptr[v + 1];
    float r0 = 0.f, r1 = 0.f;
    for (int g = gs; g < ge; ++g) {
        r0 += group_sums[2 * g + 0];
        r1 += group_sums[2 * g + 1];
        within[2 * g + 0] = r0;
        within[2 * g + 1] = r1;
    }
}

__global__ void total_k(const float* __restrict__ counts, float* __restrict__ total, int n) {
    __shared__ float buf[256];
    float s = 0.f;
    for (int i = threadIdx.x; i < n; i += 256) s += counts[i];
    buf[threadIdx.x] = s;
    __syncthreads();
    for (int off = 128; off > 0; off >>= 1) {
        if (threadIdx.x < off) buf[threadIdx.x] += buf[threadIdx.x + off];
        __syncthreads();
    }
    if (threadIdx.x == 0) total[0] = buf[0];
}

__global__ void final_k(const float* __restrict__ logprob, const float* __restrict__ within,
                        const int* __restrict__ group_id, const int* __restrict__ vog,
                        const float* __restrict__ counts, const float* __restrict__ total,
                        const int* __restrict__ place_idx, float* __restrict__ outp) {
    int p = blockIdx.x * blockDim.x + threadIdx.x;
    if (p >= PP) return;
    int g = group_id[p];
    int v = vog[g];
    float lc = logf(counts[v]) - logf(total[0]);
    int node = place_idx[p];
    atomicAdd(&outp[node * 2 + 0], logprob[p * 2 + 0] + within[g * 2 + 0] + lc);
    atomicAdd(&outp[node * 2 + 1], logprob[p * 2 + 1] + within[g * 2 + 1] + lc);
}

// ------------------------------------------------------------------
extern "C" void kernel_launch(void* const* d_in, const int* in_sizes, int n_in,
                              void* d_out, int out_size, void* d_ws, size_t ws_size,
                              hipStream_t stream) {
    const float* x          = (const float*)d_in[0];
    const float* W_enc_self = (const float*)d_in[1];
    const float* W_enc_nei  = (const float*)d_in[2];
    const float* b_enc      = (const float*)d_in[3];
    const float* W2_self    = (const float*)d_in[4];
    const float* W2_nei     = (const float*)d_in[5];
    const float* b2         = (const float*)d_in[6];
    const float* Wd1        = (const float*)d_in[7];
    const float* bd1        = (const float*)d_in[8];
    const float* Wd2        = (const float*)d_in[9];
    const float* bd2        = (const float*)d_in[10];
    const float* counts     = (const float*)d_in[11];
    const int* edge_src     = (const int*)d_in[12];
    const int* edge_dst     = (const int*)d_in[13];
    const int* place_idx    = (const int*)d_in[14];
    const int* src_idx      = (const int*)d_in[15];
    const int* t_idx        = (const int*)d_in[16];
    const int* dst_nodes    = (const int*)d_in[17];
    const int* dst_seg      = (const int*)d_in[18];
    const int* group_id     = (const int*)d_in[19];
    const int* variant_of_group = (const int*)d_in[20];
    float* outp = (float*)d_out;

    // ---- workspace layout (4-byte words), total ~66.0M words = 264 MB ----
    float* feats = (float*)d_ws;                       // 9*N*H
    float* agg   = feats + (size_t)(TT + 1) * NN * HD; // N*H
    int* zr = (int*)(agg + (size_t)NN * HD);           // zero-region start
    int* csr_counts  = zr;                             // N
    int* csr_cursor  = csr_counts + NN;                // N
    int* dst_counts  = csr_cursor + NN;                // P
    int* var_counts  = dst_counts + PP;                // V
    float* group_sums = (float*)(var_counts + VV);     // 2G
    size_t zero_words = (size_t)NN + NN + PP + VV + 2 * GG;
    int* csr_rowptr = (int*)(group_sums + 2 * GG);     // N+1
    int* dst_rowptr = csr_rowptr + (NN + 1);           // P+1
    int* var_rowptr = dst_rowptr + (PP + 1);           // V+1
    int* csr_src    = var_rowptr + (VV + 1);           // E
    float* logprob  = (float*)(csr_src + EE);          // 2P
    float* within   = logprob + 2 * PP;                // 2G
    float* total_counts = within + 2 * GG;             // 1

    hipMemsetAsync(zr, 0, zero_words * 4, stream);
    hipMemsetAsync(d_out, 0, (size_t)out_size * sizeof(float), stream);

    // ---- CSR builds ----
    count_k<<<(EE + 255) / 256, 256, 0, stream>>>(edge_dst, csr_counts, EE);
    count_k<<<(DD + 255) / 256, 256, 0, stream>>>(dst_seg, dst_counts, DD);
    count_k<<<(GG + 255) / 256, 256, 0, stream>>>(variant_of_group, var_counts, GG);
    scan_excl_k<<<1, 1024, 0, stream>>>(csr_counts, csr_rowptr, NN);
    scan_excl_k<<<1, 1024, 0, stream>>>(dst_counts, dst_rowptr, PP);
    scan_excl_k<<<1, 1024, 0, stream>>>(var_counts, var_rowptr, VV);
    fill_csr_k<<<(EE + 255) / 256, 256, 0, stream>>>(edge_src, edge_dst, csr_rowptr,
                                                     csr_cursor, csr_src, EE);

    // ---- 9 message-passing rounds ----
    for (int r = 0; r <= TT; ++r) {
        const float* hin = (r == 0) ? x : feats + (size_t)(r - 1) * NN * HD;
        int Kin          = (r == 0) ? FINN : HD;
        const float* Ws  = (r == 0) ? W_enc_self : W2_self;
        const float* Wn  = (r == 0) ? W_enc_nei : W2_nei;
        const float* bb  = (r == 0) ? b_enc : b2;
        float* hout = feats + (size_t)r * NN * HD;
        agg_k<<<NN, Kin, 0, stream>>>(hin, csr_rowptr, csr_src, agg, Kin);
        mp_gemm_k<<<(NN + 63) / 64, 256, 0, stream>>>(hin, agg, Ws, Wn, bb, hout, Kin);
    }

    // ---- fused decoder ----
    decoder_k<<<(PP + 31) / 32, 256, 0, stream>>>(feats, place_idx, src_idx, t_idx,
                                                  dst_nodes, dst_rowptr, Wd1, bd1, Wd2, bd2,
                                                  logprob);

    // ---- group / variant running-sum machinery ----
    group_sum_k<<<(PP + 255) / 256, 256, 0, stream>>>(logprob, group_id, group_sums);
    within_k<<<(VV + 255) / 256, 256, 0, stream>>>(group_sums, var_rowptr, within);
    total_k<<<1, 256, 0, stream>>>(counts, total_counts, VV);
    final_k<<<(PP + 255) / 256, 256, 0, stream>>>(logprob, within, group_id, variant_of_group,
                                                  counts, total_counts, place_idx, outp);
}

// Round 2
// 3093.186 us; speedup vs baseline: 1.8404x; 1.8404x over previous
//
#include <hip/hip_runtime.h>
#include <math.h>

#define NN 50000
#define FINN 64
#define HD 128
#define EE 800000
#define TT 8
#define PP 250000
#define DD 500000
#define GG 20000
#define VV 2000
#define OO 2

typedef short short8 __attribute__((ext_vector_type(8)));
typedef float f32x4 __attribute__((ext_vector_type(4)));

__device__ __forceinline__ unsigned short f2bf(float f) {
    unsigned int u = __float_as_uint(f);
    u += 0x7fffu + ((u >> 16) & 1u);   // round-to-nearest-even
    return (unsigned short)(u >> 16);
}

// ------------------------------------------------------------------
// utility: histogram counts for CSR build
__global__ void count_k(const int* __restrict__ idx, int* __restrict__ counts, int n) {
    int i = blockIdx.x * blockDim.x + threadIdx.x;
    if (i < n) atomicAdd(&counts[idx[i]], 1);
}

// single-block chunked exclusive scan; rowptr has n+1 entries
__global__ void scan_excl_k(const int* __restrict__ counts, int* __restrict__ rowptr, int n) {
    __shared__ int buf[1024];
    __shared__ int carry_s;
    int tid = threadIdx.x;
    if (tid == 0) carry_s = 0;
    __syncthreads();
    for (int base = 0; base < n; base += 1024) {
        int i = base + tid;
        int v = (i < n) ? counts[i] : 0;
        buf[tid] = v;
        __syncthreads();
        for (int off = 1; off < 1024; off <<= 1) {
            int t = (tid >= off) ? buf[tid - off] : 0;
            __syncthreads();
            buf[tid] += t;
            __syncthreads();
        }
        int incl = buf[tid];
        int carry = carry_s;
        if (i < n) rowptr[i] = carry + incl - v;
        __syncthreads();
        if (tid == 1023) carry_s = carry + buf[1023];
        __syncthreads();
    }
    if (tid == 0) rowptr[n] = carry_s;
}

__global__ void fill_csr_k(const int* __restrict__ esrc, const int* __restrict__ edst,
                           const int* __restrict__ rowptr, int* __restrict__ cursor,
                           int* __restrict__ outi, int n) {
    int e = blockIdx.x * blockDim.x + threadIdx.x;
    if (e < n) {
        int d = edst[e];
        int pos = atomicAdd(&cursor[d], 1);
        outi[rowptr[d] + pos] = esrc[e];
    }
}

// ------------------------------------------------------------------
// mean-aggregation: one block per node, one thread per feature
__global__ void agg_k(const float* __restrict__ h, const int* __restrict__ rowptr,
                      const int* __restrict__ csr_src, float* __restrict__ agg, int Kin) {
    int node = blockIdx.x;
    int j = threadIdx.x;
    int s = rowptr[node], e = rowptr[node + 1];
    float sum = 0.f;
    for (int i = s; i < e; ++i) {
        int src = csr_src[i];
        sum += h[(long)src * Kin + j];
    }
    float d = fmaxf((float)(e - s), 1.f);
    agg[(long)node * Kin + j] = sum / d;
}

// ------------------------------------------------------------------
// h_out = relu([hin | agg] @ [Ws ; Wn] + b)   tile: 64 rows x 128 cols
__launch_bounds__(256)
__global__ void mp_gemm_k(const float* __restrict__ hin, const float* __restrict__ agg,
                          const float* __restrict__ Ws, const float* __restrict__ Wn,
                          const float* __restrict__ bias, float* __restrict__ hout, int Kin) {
    __shared__ float At[32][65];                   // [kk][row]
    __shared__ __align__(16) float Bt[32][128];    // [kk][col]
    int tid = threadIdx.x;
    int tx = tid & 31;       // col group: cols tx*4..tx*4+3
    int ty = tid >> 5;       // row phase: rows ty + 8*i
    int row0 = blockIdx.x * 64;
    float acc[8][4] = {};
    int K = 2 * Kin;
    for (int k0 = 0; k0 < K; k0 += 32) {
        for (int l = tid; l < 64 * 32; l += 256) {
            int r = l >> 5, kk = l & 31;
            int grow = row0 + r;
            int k = k0 + kk;
            float v = 0.f;
            if (grow < NN)
                v = (k < Kin) ? hin[(long)grow * Kin + k] : agg[(long)grow * Kin + (k - Kin)];
            At[kk][r] = v;
        }
        for (int l = tid; l < 32 * 128; l += 256) {
            int kk = l >> 7, c = l & 127;
            int k = k0 + kk;
            Bt[kk][c] = (k < Kin) ? Ws[k * HD + c] : Wn[(k - Kin) * HD + c];
        }
        __syncthreads();
#pragma unroll
        for (int kk = 0; kk < 32; ++kk) {
            float4 b = *(const float4*)&Bt[kk][tx * 4];
#pragma unroll
            for (int i = 0; i < 8; ++i) {
                float a = At[kk][ty + 8 * i];
                acc[i][0] += a * b.x;
                acc[i][1] += a * b.y;
                acc[i][2] += a * b.z;
                acc[i][3] += a * b.w;
            }
        }
        __syncthreads();
    }
    float4 bv = *(const float4*)&bias[tx * 4];
#pragma unroll
    for (int i = 0; i < 8; ++i) {
        int grow = row0 + ty + 8 * i;
        if (grow < NN) {
            float4 o;
            o.x = fmaxf(acc[i][0] + bv.x, 0.f);
            o.y = fmaxf(acc[i][1] + bv.y, 0.f);
            o.z = fmaxf(acc[i][2] + bv.z, 0.f);
            o.w = fmaxf(acc[i][3] + bv.w, 0.f);
            *(float4*)&hout[(long)grow * HD + tx * 4] = o;
        }
    }
}

// ------------------------------------------------------------------
// Wd1t[n][k] = bf16(Wd1[k][n])  (B operand for MFMA wants [n][k] bf16)
__global__ void wd1t_k(const float* __restrict__ Wd1, unsigned short* __restrict__ Wd1t) {
    int i = blockIdx.x * blockDim.x + threadIdx.x;
    if (i < 384 * 384) {
        int n = i / 384, k = i - n * 384;
        Wd1t[n * 384 + k] = f2bf(Wd1[k * 384 + n]);
    }
}

// ------------------------------------------------------------------
// fused decoder: gather cat(64x384) -> bf16 LDS -> MFMA GEMM vs Wd1t (global, L2)
// -> relu -> Wd2 -> log_softmax.  Block: 256 thr = 4 waves; wave w owns cols
// w*96..w*96+95 (6 n-tiles of 16), all 64 rows (4 m-subtiles of 16).
// MFMA 16x16x32 bf16: A[m=lane&15][k=(lane>>4)*8+j], B[k][n=lane&15],
// D col=lane&15, row=(lane>>4)*4+reg  (m89-verified mapping).
__launch_bounds__(256)
__global__ void dec_gemm_k(const float* __restrict__ feats,
                           const int* __restrict__ place_idx, const int* __restrict__ src_idx,
                           const int* __restrict__ t_idx, const int* __restrict__ dst_nodes,
                           const int* __restrict__ dst_rowptr,
                           const unsigned short* __restrict__ Wd1t,
                           const float* __restrict__ bd1, const float* __restrict__ Wd2,
                           const float* __restrict__ bd2, float* __restrict__ logprob) {
    __shared__ unsigned short catL[64 * 392];   // 64 rows x 384, stride 392 (16B-aligned rows)
    __shared__ float lpart[4][64][2];
    int tid = threadIdx.x;
    int p0 = blockIdx.x * 64;

    // ---- gather phase: place/src ----
    for (int l = tid; l < 64 * 32; l += 256) {
        int r = l >> 5, c = (l & 31) * 4;
        int p = p0 + r;
        float4 pv = {0, 0, 0, 0}, sv = {0, 0, 0, 0};
        if (p < PP) {
            long t = t_idx[p];
            pv = *(const float4*)(feats + ((t * NN + place_idx[p]) * (long)HD + c));
            sv = *(const float4*)(feats + ((t * NN + src_idx[p]) * (long)HD + c));
        }
        ushort4 pw = {f2bf(pv.x), f2bf(pv.y), f2bf(pv.z), f2bf(pv.w)};
        ushort4 sw = {f2bf(sv.x), f2bf(sv.y), f2bf(sv.z), f2bf(sv.w)};
        *(ushort4*)&catL[r * 392 + c] = pw;
        *(ushort4*)&catL[r * 392 + 128 + c] = sw;
    }
    // ---- gather phase: dst segment-sum ----
    for (int l = tid; l < 64 * 32; l += 256) {
        int r = l >> 5, c = (l & 31) * 4;
        int p = p0 + r;
        float4 s = {0, 0, 0, 0};
        if (p < PP) {
            long t = t_idx[p];
            int js = dst_rowptr[p], je = dst_rowptr[p + 1];
            for (int j = js; j < je; ++j) {
                float4 v = *(const float4*)(feats + ((t * NN + dst_nodes[j]) * (long)HD + c));
                s.x += v.x; s.y += v.y; s.z += v.z; s.w += v.w;
            }
        }
        ushort4 sw = {f2bf(s.x), f2bf(s.y), f2bf(s.z), f2bf(s.w)};
        *(ushort4*)&catL[r * 392 + 256 + c] = sw;
    }
    __syncthreads();

    // ---- MFMA GEMM ----
    int lane = tid & 63;
    int w = tid >> 6;
    int cc = lane & 15;   // A-row within subtile / B-col within n-tile
    int g = lane >> 4;    // k-quad (8 elems each)
    f32x4 acc[4][6];
#pragma unroll
    for (int s = 0; s < 4; ++s)
#pragma unroll
        for (int t = 0; t < 6; ++t) acc[s][t] = (f32x4){0.f, 0.f, 0.f, 0.f};

    const unsigned short* bbase = Wd1t + ((long)(w * 96 + cc) * 384 + g * 8);

    for (int k0 = 0; k0 < 384; k0 += 32) {
        short8 a[4];
#pragma unroll
        for (int s = 0; s < 4; ++s)
            a[s] = *(const short8*)&catL[(s * 16 + cc) * 392 + k0 + g * 8];
#pragma unroll
        for (int t = 0; t < 6; ++t) {
            short8 b = *(const short8*)(bbase + (long)t * 16 * 384 + k0);
#pragma unroll
            for (int s = 0; s < 4; ++s)
                acc[s][t] = __builtin_amdgcn_mfma_f32_16x16x32_bf16(a[s], b, acc[s][t], 0, 0, 0);
        }
    }

    // ---- epilogue: bias + relu + Wd2, reduce over cols ----
    float part[4][4][2] = {};
#pragma unroll
    for (int t = 0; t < 6; ++t) {
        int col = w * 96 + t * 16 + cc;
        float b1 = bd1[col];
        float w0 = Wd2[col * 2 + 0], w1 = Wd2[col * 2 + 1];
#pragma unroll
        for (int s = 0; s < 4; ++s)
#pragma unroll
            for (int r = 0; r < 4; ++r) {
                float h = fmaxf(acc[s][t][r] + b1, 0.f);
                part[s][r][0] += h * w0;
                part[s][r][1] += h * w1;
            }
    }
#pragma unroll
    for (int m = 1; m < 16; m <<= 1) {
#pragma unroll
        for (int s = 0; s < 4; ++s)
#pragma unroll
            for (int r = 0; r < 4; ++r) {
                part[s][r][0] += __shfl_xor(part[s][r][0], m);
                part[s][r][1] += __shfl_xor(part[s][r][1], m);
            }
    }
    if (cc == 0) {
#pragma unroll
        for (int s = 0; s < 4; ++s)
#pragma unroll
            for (int r = 0; r < 4; ++r) {
                int row = s * 16 + g * 4 + r;
                lpart[w][row][0] = part[s][r][0];
                lpart[w][row][1] = part[s][r][1];
            }
    }
    __syncthreads();
    if (tid < 64) {
        int p = p0 + tid;
        if (p < PP) {
            float l0 = lpart[0][tid][0] + lpart[1][tid][0] + lpart[2][tid][0] + lpart[3][tid][0] + bd2[0];
            float l1 = lpart[0][tid][1] + lpart[1][tid][1] + lpart[2][tid][1] + lpart[3][tid][1] + bd2[1];
            float m = fmaxf(l0, l1);
            float lse = m + logf(expf(l0 - m) + expf(l1 - m));
            logprob[p * 2 + 0] = l0 - lse;
            logprob[p * 2 + 1] = l1 - lse;
        }
    }
}

// ------------------------------------------------------------------
__global__ void group_sum_k(const float* __restrict__ logprob, const int* __restrict__ group_id,
                            float* __restrict__ group_sums) {
    int p = blockIdx.x * blockDim.x + threadIdx.x;
    if (p >= PP) return;
    int g = group_id[p];
    atomicAdd(&group_sums[g * 2 + 0], logprob[p * 2 + 0]);
    atomicAdd(&group_sums[g * 2 + 1], logprob[p * 2 + 1]);
}

// segmented inclusive cumsum within each variant's contiguous group range
__global__ void within_k(const float* __restrict__ group_sums, const int* __restrict__ var_rowptr,
                         float* __restrict__ within) {
    int v = blockIdx.x * blockDim.x + threadIdx.x;
    if (v >= VV) return;
    int gs = var_rowptr[v], ge = var_rowptr[v + 1];
    float r0 = 0.f, r1 = 0.f;
    for (int g = gs; g < ge; ++g) {
        r0 += group_sums[2 * g + 0];
        r1 += group_sums[2 * g + 1];
        within[2 * g + 0] = r0;
        within[2 * g + 1] = r1;
    }
}

__global__ void total_k(const float* __restrict__ counts, float* __restrict__ total, int n) {
    __shared__ float buf[256];
    float s = 0.f;
    for (int i = threadIdx.x; i < n; i += 256) s += counts[i];
    buf[threadIdx.x] = s;
    __syncthreads();
    for (int off = 128; off > 0; off >>= 1) {
        if (threadIdx.x < off) buf[threadIdx.x] += buf[threadIdx.x + off];
        __syncthreads();
    }
    if (threadIdx.x == 0) total[0] = buf[0];
}

__global__ void final_k(const float* __restrict__ logprob, const float* __restrict__ within,
                        const int* __restrict__ group_id, const int* __restrict__ vog,
                        const float* __restrict__ counts, const float* __restrict__ total,
                        const int* __restrict__ place_idx, float* __restrict__ outp) {
    int p = blockIdx.x * blockDim.x + threadIdx.x;
    if (p >= PP) return;
    int g = group_id[p];
    int v = vog[g];
    float lc = logf(counts[v]) - logf(total[0]);
    int node = place_idx[p];
    atomicAdd(&outp[node * 2 + 0], logprob[p * 2 + 0] + within[g * 2 + 0] + lc);
    atomicAdd(&outp[node * 2 + 1], logprob[p * 2 + 1] + within[g * 2 + 1] + lc);
}

// ------------------------------------------------------------------
extern "C" void kernel_launch(void* const* d_in, const int* in_sizes, int n_in,
                              void* d_out, int out_size, void* d_ws, size_t ws_size,
                              hipStream_t stream) {
    const float* x          = (const float*)d_in[0];
    const float* W_enc_self = (const float*)d_in[1];
    const float* W_enc_nei  = (const float*)d_in[2];
    const float* b_enc      = (const float*)d_in[3];
    const float* W2_self    = (const float*)d_in[4];
    const float* W2_nei     = (const float*)d_in[5];
    const float* b2         = (const float*)d_in[6];
    const float* Wd1        = (const float*)d_in[7];
    const float* bd1        = (const float*)d_in[8];
    const float* Wd2        = (const float*)d_in[9];
    const float* bd2        = (const float*)d_in[10];
    const float* counts     = (const float*)d_in[11];
    const int* edge_src     = (const int*)d_in[12];
    const int* edge_dst     = (const int*)d_in[13];
    const int* place_idx    = (const int*)d_in[14];
    const int* src_idx      = (const int*)d_in[15];
    const int* t_idx        = (const int*)d_in[16];
    const int* dst_nodes    = (const int*)d_in[17];
    const int* dst_seg      = (const int*)d_in[18];
    const int* group_id     = (const int*)d_in[19];
    const int* variant_of_group = (const int*)d_in[20];
    float* outp = (float*)d_out;

    // ---- workspace layout (4-byte words) ----
    float* feats = (float*)d_ws;                       // 9*N*H
    float* agg   = feats + (size_t)(TT + 1) * NN * HD; // N*H
    int* zr = (int*)(agg + (size_t)NN * HD);           // zero-region start
    int* csr_counts  = zr;                             // N
    int* csr_cursor  = csr_counts + NN;                // N
    int* dst_counts  = csr_cursor + NN;                // P
    int* var_counts  = dst_counts + PP;                // V
    float* group_sums = (float*)(var_counts + VV);     // 2G
    size_t zero_words = (size_t)NN + NN + PP + VV + 2 * GG;
    int* csr_rowptr = (int*)(group_sums + 2 * GG);     // N+1
    int* dst_rowptr = csr_rowptr + (NN + 1);           // P+1
    int* var_rowptr = dst_rowptr + (PP + 1);           // V+1
    int* csr_src    = var_rowptr + (VV + 1);           // E
    float* logprob  = (float*)(csr_src + EE);          // 2P
    float* within   = logprob + 2 * PP;                // 2G
    float* total_counts = within + 2 * GG;             // 1
    unsigned short* wd1t = (unsigned short*)(total_counts + 1); // 384*384 bf16

    hipMemsetAsync(zr, 0, zero_words * 4, stream);
    hipMemsetAsync(d_out, 0, (size_t)out_size * sizeof(float), stream);

    // ---- CSR builds + weight transpose ----
    count_k<<<(EE + 255) / 256, 256, 0, stream>>>(edge_dst, csr_counts, EE);
    count_k<<<(DD + 255) / 256, 256, 0, stream>>>(dst_seg, dst_counts, DD);
    count_k<<<(GG + 255) / 256, 256, 0, stream>>>(variant_of_group, var_counts, GG);
    wd1t_k<<<(384 * 384 + 255) / 256, 256, 0, stream>>>(Wd1, wd1t);
    scan_excl_k<<<1, 1024, 0, stream>>>(csr_counts, csr_rowptr, NN);
    scan_excl_k<<<1, 1024, 0, stream>>>(dst_counts, dst_rowptr, PP);
    scan_excl_k<<<1, 1024, 0, stream>>>(var_counts, var_rowptr, VV);
    fill_csr_k<<<(EE + 255) / 256, 256, 0, stream>>>(edge_src, edge_dst, csr_rowptr,
                                                     csr_cursor, csr_src, EE);

    // ---- 9 message-passing rounds ----
    for (int r = 0; r <= TT; ++r) {
        const float* hin = (r == 0) ? x : feats + (size_t)(r - 1) * NN * HD;
        int Kin          = (r == 0) ? FINN : HD;
        const float* Ws  = (r == 0) ? W_enc_self : W2_self;
        const float* Wn  = (r == 0) ? W_enc_nei : W2_nei;
        const float* bb  = (r == 0) ? b_enc : b2;
        float* hout = feats + (size_t)r * NN * HD;
        agg_k<<<NN, Kin, 0, stream>>>(hin, csr_rowptr, csr_src, agg, Kin);
        mp_gemm_k<<<(NN + 63) / 64, 256, 0, stream>>>(hin, agg, Ws, Wn, bb, hout, Kin);
    }

    // ---- fused MFMA decoder ----
    dec_gemm_k<<<(PP + 63) / 64, 256, 0, stream>>>(feats, place_idx, src_idx, t_idx,
                                                   dst_nodes, dst_rowptr, wd1t, bd1, Wd2, bd2,
                                                   logprob);

    // ---- group / variant running-sum machinery ----
    group_sum_k<<<(PP + 255) / 256, 256, 0, stream>>>(logprob, group_id, group_sums);
    within_k<<<(VV + 255) / 256, 256, 0, stream>>>(group_sums, var_rowptr, within);
    total_k<<<1, 256, 0, stream>>>(counts, total_counts, VV);
    final_k<<<(PP + 255) / 256, 256, 0, stream>>>(logprob, within, group_id, variant_of_group,
                                                  counts, total_counts, place_idx, outp);
}

// Round 3
// 1825.554 us; speedup vs baseline: 3.1183x; 1.6944x over previous
//
#include <hip/hip_runtime.h>
#include <math.h>

#define NN 50000
#define FINN 64
#define HD 128
#define EE 800000
#define TT 8
#define PP 250000
#define DD 500000
#define GG 20000
#define VV 2000
#define OO 2

typedef short short8 __attribute__((ext_vector_type(8)));
typedef float f32x4 __attribute__((ext_vector_type(4)));

__device__ __forceinline__ unsigned short f2bf(float f) {
    unsigned int u = __float_as_uint(f);
    u += 0x7fffu + ((u >> 16) & 1u);   // round-to-nearest-even
    return (unsigned short)(u >> 16);
}
__device__ __forceinline__ float bf2f(unsigned short u) {
    return __uint_as_float(((unsigned int)u) << 16);
}

// ------------------------------------------------------------------
__global__ void count_k(const int* __restrict__ idx, int* __restrict__ counts, int n) {
    int i = blockIdx.x * blockDim.x + threadIdx.x;
    if (i < n) atomicAdd(&counts[idx[i]], 1);
}

// ---- 3-phase parallel exclusive scan for edge CSR rowptr ----
__global__ void blk_sum_k(const int* __restrict__ counts, int n, int* __restrict__ bsum) {
    __shared__ int buf[256];
    int t = threadIdx.x, i = blockIdx.x * 256 + t;
    buf[t] = (i < n) ? counts[i] : 0;
    __syncthreads();
    for (int off = 128; off > 0; off >>= 1) {
        if (t < off) buf[t] += buf[t + off];
        __syncthreads();
    }
    if (t == 0) bsum[blockIdx.x] = buf[0];
}

__global__ void scan_small_k(const int* __restrict__ bsum, int nb, int* __restrict__ boff) {
    __shared__ int buf[256];
    int t = threadIdx.x;
    int v = (t < nb) ? bsum[t] : 0;
    buf[t] = v;
    __syncthreads();
    for (int off = 1; off < 256; off <<= 1) {
        int u = (t >= off) ? buf[t - off] : 0;
        __syncthreads();
        buf[t] += u;
        __syncthreads();
    }
    if (t < nb) boff[t] = buf[t] - v;
}

__global__ void rowptr_fill_k(const int* __restrict__ counts, const int* __restrict__ boff,
                              int n, int* __restrict__ rowptr, int total) {
    __shared__ int buf[256];
    int t = threadIdx.x, i = blockIdx.x * 256 + t;
    int v = (i < n) ? counts[i] : 0;
    buf[t] = v;
    __syncthreads();
    for (int off = 1; off < 256; off <<= 1) {
        int u = (t >= off) ? buf[t - off] : 0;
        __syncthreads();
        buf[t] += u;
        __syncthreads();
    }
    if (i < n) rowptr[i] = boff[blockIdx.x] + buf[t] - v;
    if (i == 0) rowptr[n] = total;
}

// rowptr for SORTED arrays: rowptr[i] = lower_bound(arr, i), i in [0, m]
__global__ void lb_rowptr_k(const int* __restrict__ arr, int n, int* __restrict__ rowptr, int m) {
    int i = blockIdx.x * blockDim.x + threadIdx.x;
    if (i > m) return;
    int lo = 0, hi = n;
    while (lo < hi) {
        int mid = (lo + hi) >> 1;
        if (arr[mid] < i) lo = mid + 1; else hi = mid;
    }
    rowptr[i] = lo;
}

__global__ void fill_csr_k(const int* __restrict__ esrc, const int* __restrict__ edst,
                           const int* __restrict__ rowptr, int* __restrict__ cursor,
                           int* __restrict__ outi, int n) {
    int e = blockIdx.x * blockDim.x + threadIdx.x;
    if (e < n) {
        int d = edst[e];
        int pos = atomicAdd(&cursor[d], 1);
        outi[rowptr[d] + pos] = esrc[e];
    }
}

// ------------------------------------------------------------------
// convert x to bf16
__global__ void xbf_k(const float* __restrict__ x, unsigned short* __restrict__ xb, int n) {
    int i = blockIdx.x * blockDim.x + threadIdx.x;
    if (i < n) xb[i] = f2bf(x[i]);
}

// combined transposed weights Wt[c][k] bf16, k = [self | nei]
__global__ void wt_k(const float* __restrict__ Ws, const float* __restrict__ Wn,
                     unsigned short* __restrict__ Wt, int Kin) {
    int i = blockIdx.x * blockDim.x + threadIdx.x;
    int K = 2 * Kin;
    if (i < HD * K) {
        int c = i / K, k = i - c * K;
        Wt[i] = f2bf((k < Kin) ? Ws[k * HD + c] : Wn[(k - Kin) * HD + c]);
    }
}

// Wd1t[n][k] = bf16(Wd1[k][n])
__global__ void wd1t_k(const float* __restrict__ Wd1, unsigned short* __restrict__ Wd1t) {
    int i = blockIdx.x * blockDim.x + threadIdx.x;
    if (i < 384 * 384) {
        int n = i / 384, k = i - n * 384;
        Wd1t[n * 384 + k] = f2bf(Wd1[k * 384 + n]);
    }
}

// ------------------------------------------------------------------
// mean-aggregation, bf16 in/out: 1 wave per node, lane covers 2 features
__launch_bounds__(256)
__global__ void agg_bf_k(const unsigned short* __restrict__ h, const int* __restrict__ rowptr,
                         const int* __restrict__ csr_src, unsigned short* __restrict__ aggout,
                         int Kin) {
    int node = blockIdx.x * 4 + (threadIdx.x >> 6);
    int lane = threadIdx.x & 63;
    if (node >= NN || lane * 2 >= Kin) return;
    int s = rowptr[node], e = rowptr[node + 1];
    float s0 = 0.f, s1 = 0.f;
    for (int i = s; i < e; ++i) {
        int src = csr_src[i];
        ushort2 v = *(const ushort2*)&h[(size_t)src * Kin + lane * 2];
        s0 += bf2f(v.x);
        s1 += bf2f(v.y);
    }
    float d = fmaxf((float)(e - s), 1.f);
    ushort2 o = {f2bf(s0 / d), f2bf(s1 / d)};
    *(ushort2*)&aggout[(size_t)node * Kin + lane * 2] = o;
}

// ------------------------------------------------------------------
// h_out = relu([hin | agg] @ Wt^T + b), bf16 MFMA, no LDS.
// Block 256 = 4 waves; wave w: rows w*16..+15 of a 64-row block-tile, all 128 cols.
// MFMA 16x16x32 bf16: A[m=lane&15][k=quad*8+j], B[n=lane&15][k], D col=lane&15,row=quad*4+reg.
__launch_bounds__(256)
__global__ void mp_mfma_k(const unsigned short* __restrict__ hin,
                          const unsigned short* __restrict__ aggin,
                          const unsigned short* __restrict__ Wt,
                          const float* __restrict__ bias,
                          unsigned short* __restrict__ hout, int Kin) {
    int tid = threadIdx.x;
    int lane = tid & 63, w = tid >> 6;
    int cc = lane & 15, g = lane >> 4;
    int K = 2 * Kin;
    int rowA = blockIdx.x * 64 + w * 16 + cc;
    bool rowok = rowA < NN;
    const unsigned short* hrow = hin + (size_t)rowA * Kin;
    const unsigned short* arow = aggin + (size_t)rowA * Kin;

    f32x4 acc[8];
#pragma unroll
    for (int t = 0; t < 8; ++t) acc[t] = (f32x4){0.f, 0.f, 0.f, 0.f};

    for (int k0 = 0; k0 < K; k0 += 32) {
        int k = k0 + g * 8;
        short8 a = {0, 0, 0, 0, 0, 0, 0, 0};
        if (rowok)
            a = *(const short8*)((k < Kin) ? (hrow + k) : (arow + (k - Kin)));
#pragma unroll
        for (int t = 0; t < 8; ++t) {
            short8 b = *(const short8*)&Wt[(size_t)(t * 16 + cc) * K + k];
            acc[t] = __builtin_amdgcn_mfma_f32_16x16x32_bf16(a, b, acc[t], 0, 0, 0);
        }
    }
#pragma unroll
    for (int t = 0; t < 8; ++t) {
        int col = t * 16 + cc;
        float b1 = bias[col];
#pragma unroll
        for (int r = 0; r < 4; ++r) {
            int grow = blockIdx.x * 64 + w * 16 + g * 4 + r;
            if (grow < NN)
                hout[(size_t)grow * HD + col] = f2bf(fmaxf(acc[t][r] + b1, 0.f));
        }
    }
}

// ------------------------------------------------------------------
// fused decoder: gather cat(64x384 bf16) -> LDS -> MFMA vs Wd1t -> relu -> Wd2 -> log_softmax
__launch_bounds__(256)
__global__ void dec_gemm_k(const unsigned short* __restrict__ feats,
                           const int* __restrict__ place_idx, const int* __restrict__ src_idx,
                           const int* __restrict__ t_idx, const int* __restrict__ dst_nodes,
                           const int* __restrict__ dst_rowptr,
                           const unsigned short* __restrict__ Wd1t,
                           const float* __restrict__ bd1, const float* __restrict__ Wd2,
                           const float* __restrict__ bd2, float* __restrict__ logprob) {
    __shared__ unsigned short catL[64 * 392];
    __shared__ float lpart[4][64][2];
    int tid = threadIdx.x;
    int p0 = blockIdx.x * 64;

    // ---- gather: place & src (bf16 rows, straight copies) ----
    for (int l = tid; l < 64 * 32; l += 256) {
        int r = l >> 5, c = (l & 31) * 4;
        int p = p0 + r;
        ushort4 pv = {0, 0, 0, 0}, sv = {0, 0, 0, 0};
        if (p < PP) {
            long t = t_idx[p];
            pv = *(const ushort4*)(feats + ((t * NN + place_idx[p]) * (long)HD + c));
            sv = *(const ushort4*)(feats + ((t * NN + src_idx[p]) * (long)HD + c));
        }
        *(ushort4*)&catL[r * 392 + c] = pv;
        *(ushort4*)&catL[r * 392 + 128 + c] = sv;
    }
    // ---- gather: dst segment-sum (fp32 accumulate) ----
    for (int l = tid; l < 64 * 32; l += 256) {
        int r = l >> 5, c = (l & 31) * 4;
        int p = p0 + r;
        float s0 = 0.f, s1 = 0.f, s2 = 0.f, s3 = 0.f;
        if (p < PP) {
            long t = t_idx[p];
            int js = dst_rowptr[p], je = dst_rowptr[p + 1];
            for (int j = js; j < je; ++j) {
                ushort4 v = *(const ushort4*)(feats + ((t * NN + dst_nodes[j]) * (long)HD + c));
                s0 += bf2f(v.x); s1 += bf2f(v.y); s2 += bf2f(v.z); s3 += bf2f(v.w);
            }
        }
        ushort4 sw = {f2bf(s0), f2bf(s1), f2bf(s2), f2bf(s3)};
        *(ushort4*)&catL[r * 392 + 256 + c] = sw;
    }
    __syncthreads();

    // ---- MFMA GEMM: wave w owns cols w*96..+95 (6 n-tiles), all 64 rows ----
    int lane = tid & 63;
    int w = tid >> 6;
    int cc = lane & 15;
    int g = lane >> 4;
    f32x4 acc[4][6];
#pragma unroll
    for (int s = 0; s < 4; ++s)
#pragma unroll
        for (int t = 0; t < 6; ++t) acc[s][t] = (f32x4){0.f, 0.f, 0.f, 0.f};

    const unsigned short* bbase = Wd1t + ((long)(w * 96 + cc) * 384 + g * 8);

    for (int k0 = 0; k0 < 384; k0 += 32) {
        short8 a[4];
#pragma unroll
        for (int s = 0; s < 4; ++s)
            a[s] = *(const short8*)&catL[(s * 16 + cc) * 392 + k0 + g * 8];
#pragma unroll
        for (int t = 0; t < 6; ++t) {
            short8 b = *(const short8*)(bbase + (long)t * 16 * 384 + k0);
#pragma unroll
            for (int s = 0; s < 4; ++s)
                acc[s][t] = __builtin_amdgcn_mfma_f32_16x16x32_bf16(a[s], b, acc[s][t], 0, 0, 0);
        }
    }

    // ---- epilogue: bias + relu + Wd2, reduce over cols ----
    float part[4][4][2] = {};
#pragma unroll
    for (int t = 0; t < 6; ++t) {
        int col = w * 96 + t * 16 + cc;
        float b1 = bd1[col];
        float w0 = Wd2[col * 2 + 0], w1 = Wd2[col * 2 + 1];
#pragma unroll
        for (int s = 0; s < 4; ++s)
#pragma unroll
            for (int r = 0; r < 4; ++r) {
                float h = fmaxf(acc[s][t][r] + b1, 0.f);
                part[s][r][0] += h * w0;
                part[s][r][1] += h * w1;
            }
    }
#pragma unroll
    for (int m = 1; m < 16; m <<= 1) {
#pragma unroll
        for (int s = 0; s < 4; ++s)
#pragma unroll
            for (int r = 0; r < 4; ++r) {
                part[s][r][0] += __shfl_xor(part[s][r][0], m);
                part[s][r][1] += __shfl_xor(part[s][r][1], m);
            }
    }
    if (cc == 0) {
#pragma unroll
        for (int s = 0; s < 4; ++s)
#pragma unroll
            for (int r = 0; r < 4; ++r) {
                int row = s * 16 + g * 4 + r;
                lpart[w][row][0] = part[s][r][0];
                lpart[w][row][1] = part[s][r][1];
            }
    }
    __syncthreads();
    if (tid < 64) {
        int p = p0 + tid;
        if (p < PP) {
            float l0 = lpart[0][tid][0] + lpart[1][tid][0] + lpart[2][tid][0] + lpart[3][tid][0] + bd2[0];
            float l1 = lpart[0][tid][1] + lpart[1][tid][1] + lpart[2][tid][1] + lpart[3][tid][1] + bd2[1];
            float m = fmaxf(l0, l1);
            float lse = m + logf(expf(l0 - m) + expf(l1 - m));
            logprob[p * 2 + 0] = l0 - lse;
            logprob[p * 2 + 1] = l1 - lse;
        }
    }
}

// ------------------------------------------------------------------
__global__ void group_sum_k(const float* __restrict__ logprob, const int* __restrict__ group_id,
                            float* __restrict__ group_sums) {
    int p = blockIdx.x * blockDim.x + threadIdx.x;
    if (p >= PP) return;
    int g = group_id[p];
    atomicAdd(&group_sums[g * 2 + 0], logprob[p * 2 + 0]);
    atomicAdd(&group_sums[g * 2 + 1], logprob[p * 2 + 1]);
}

__global__ void within_k(const float* __restrict__ group_sums, const int* __restrict__ var_rowptr,
                         float* __restrict__ within) {
    int v = blockIdx.x * blockDim.x + threadIdx.x;
    if (v >= VV) return;
    int gs = var_rowptr[v], ge = var_rowptr[v + 1];
    float r0 = 0.f, r1 = 0.f;
    for (int g = gs; g < ge; ++g) {
        r0 += group_sums[2 * g + 0];
        r1 += group_sums[2 * g + 1];
        within[2 * g + 0] = r0;
        within[2 * g + 1] = r1;
    }
}

__global__ void total_k(const float* __restrict__ counts, float* __restrict__ total, int n) {
    __shared__ float buf[256];
    float s = 0.f;
    for (int i = threadIdx.x; i < n; i += 256) s += counts[i];
    buf[threadIdx.x] = s;
    __syncthreads();
    for (int off = 128; off > 0; off >>= 1) {
        if (threadIdx.x < off) buf[threadIdx.x] += buf[threadIdx.x + off];
        __syncthreads();
    }
    if (threadIdx.x == 0) total[0] = buf[0];
}

__global__ void final_k(const float* __restrict__ logprob, const float* __restrict__ within,
                        const int* __restrict__ group_id, const int* __restrict__ vog,
                        const float* __restrict__ counts, const float* __restrict__ total,
                        const int* __restrict__ place_idx, float* __restrict__ outp) {
    int p = blockIdx.x * blockDim.x + threadIdx.x;
    if (p >= PP) return;
    int g = group_id[p];
    int v = vog[g];
    float lc = logf(counts[v]) - logf(total[0]);
    int node = place_idx[p];
    atomicAdd(&outp[node * 2 + 0], logprob[p * 2 + 0] + within[g * 2 + 0] + lc);
    atomicAdd(&outp[node * 2 + 1], logprob[p * 2 + 1] + within[g * 2 + 1] + lc);
}

// ------------------------------------------------------------------
extern "C" void kernel_launch(void* const* d_in, const int* in_sizes, int n_in,
                              void* d_out, int out_size, void* d_ws, size_t ws_size,
                              hipStream_t stream) {
    const float* x          = (const float*)d_in[0];
    const float* W_enc_self = (const float*)d_in[1];
    const float* W_enc_nei  = (const float*)d_in[2];
    const float* b_enc      = (const float*)d_in[3];
    const float* W2_self    = (const float*)d_in[4];
    const float* W2_nei     = (const float*)d_in[5];
    const float* b2         = (const float*)d_in[6];
    const float* Wd1        = (const float*)d_in[7];
    const float* bd1        = (const float*)d_in[8];
    const float* Wd2        = (const float*)d_in[9];
    const float* bd2        = (const float*)d_in[10];
    const float* counts     = (const float*)d_in[11];
    const int* edge_src     = (const int*)d_in[12];
    const int* edge_dst     = (const int*)d_in[13];
    const int* place_idx    = (const int*)d_in[14];
    const int* src_idx      = (const int*)d_in[15];
    const int* t_idx        = (const int*)d_in[16];
    const int* dst_nodes    = (const int*)d_in[17];
    const int* dst_seg      = (const int*)d_in[18];
    const int* group_id     = (const int*)d_in[19];
    const int* variant_of_group = (const int*)d_in[20];
    float* outp = (float*)d_out;

    const int NB = (NN + 255) / 256;   // 196 scan blocks

    // ---- workspace layout ----
    unsigned short* feats = (unsigned short*)d_ws;           // 9*N*H bf16
    unsigned short* aggb  = feats + (size_t)(TT + 1) * NN * HD; // N*H
    unsigned short* xb    = aggb + (size_t)NN * HD;          // N*FIN
    unsigned short* wenc_t = xb + (size_t)NN * FINN;         // 128*128
    unsigned short* w2_t   = wenc_t + HD * 2 * FINN;         // 128*256
    unsigned short* wd1t   = w2_t + HD * 2 * HD;             // 384*384
    int* zr = (int*)(wd1t + 384 * 384);                      // zero-region start
    int* csr_counts   = zr;                                  // N
    int* csr_cursor   = csr_counts + NN;                     // N
    float* group_sums = (float*)(csr_cursor + NN);           // 2G
    size_t zero_words = (size_t)NN + NN + 2 * GG;
    int* bsum       = (int*)(group_sums + 2 * GG);           // 256
    int* boff       = bsum + 256;                            // 256
    int* csr_rowptr = boff + 256;                            // N+1
    int* dst_rowptr = csr_rowptr + (NN + 1);                 // P+1
    int* var_rowptr = dst_rowptr + (PP + 1);                 // V+1
    int* csr_src    = var_rowptr + (VV + 1);                 // E
    float* logprob  = (float*)(csr_src + EE);                // 2P
    float* within   = logprob + 2 * PP;                      // 2G
    float* total_counts = within + 2 * GG;                   // 1

    hipMemsetAsync(zr, 0, zero_words * 4, stream);
    hipMemsetAsync(d_out, 0, (size_t)out_size * sizeof(float), stream);

    // ---- prep: conversions, transposes, CSRs ----
    xbf_k<<<(NN * FINN + 255) / 256, 256, 0, stream>>>(x, xb, NN * FINN);
    wt_k<<<(HD * 2 * FINN + 255) / 256, 256, 0, stream>>>(W_enc_self, W_enc_nei, wenc_t, FINN);
    wt_k<<<(HD * 2 * HD + 255) / 256, 256, 0, stream>>>(W2_self, W2_nei, w2_t, HD);
    wd1t_k<<<(384 * 384 + 255) / 256, 256, 0, stream>>>(Wd1, wd1t);

    count_k<<<(EE + 255) / 256, 256, 0, stream>>>(edge_dst, csr_counts, EE);
    blk_sum_k<<<NB, 256, 0, stream>>>(csr_counts, NN, bsum);
    scan_small_k<<<1, 256, 0, stream>>>(bsum, NB, boff);
    rowptr_fill_k<<<NB, 256, 0, stream>>>(csr_counts, boff, NN, csr_rowptr, EE);
    fill_csr_k<<<(EE + 255) / 256, 256, 0, stream>>>(edge_src, edge_dst, csr_rowptr,
                                                     csr_cursor, csr_src, EE);
    lb_rowptr_k<<<(PP + 256) / 256, 256, 0, stream>>>(dst_seg, DD, dst_rowptr, PP);
    lb_rowptr_k<<<(VV + 256) / 256, 256, 0, stream>>>(variant_of_group, GG, var_rowptr, VV);

    // ---- 9 message-passing rounds (bf16) ----
    for (int r = 0; r <= TT; ++r) {
        const unsigned short* hin = (r == 0) ? xb : feats + (size_t)(r - 1) * NN * HD;
        int Kin                   = (r == 0) ? FINN : HD;
        const unsigned short* Wt  = (r == 0) ? wenc_t : w2_t;
        const float* bb           = (r == 0) ? b_enc : b2;
        unsigned short* hout = feats + (size_t)r * NN * HD;
        agg_bf_k<<<(NN + 3) / 4, 256, 0, stream>>>(hin, csr_rowptr, csr_src, aggb, Kin);
        mp_mfma_k<<<(NN + 63) / 64, 256, 0, stream>>>(hin, aggb, Wt, bb, hout, Kin);
    }

    // ---- fused MFMA decoder ----
    dec_gemm_k<<<(PP + 63) / 64, 256, 0, stream>>>(feats, place_idx, src_idx, t_idx,
                                                   dst_nodes, dst_rowptr, wd1t, bd1, Wd2, bd2,
                                                   logprob);

    // ---- group / variant running-sum machinery ----
    group_sum_k<<<(PP + 255) / 256, 256, 0, stream>>>(logprob, group_id, group_sums);
    within_k<<<(VV + 255) / 256, 256, 0, stream>>>(group_sums, var_rowptr, within);
    total_k<<<1, 256, 0, stream>>>(counts, total_counts, VV);
    final_k<<<(PP + 255) / 256, 256, 0, stream>>>(logprob, within, group_id, variant_of_group,
                                                  counts, total_counts, place_idx, outp);
}

// Round 4
// 1298.626 us; speedup vs baseline: 4.3836x; 1.4058x over previous
//
#include <hip/hip_runtime.h>
#include <math.h>

#define NN 50000
#define FINN 64
#define HD 128
#define EE 800000
#define TT 8
#define PP 250000
#define DD 500000
#define GG 20000
#define VV 2000
#define OO 2

typedef short short8 __attribute__((ext_vector_type(8)));
typedef float f32x4 __attribute__((ext_vector_type(4)));

__device__ __forceinline__ unsigned short f2bf(float f) {
    unsigned int u = __float_as_uint(f);
    u += 0x7fffu + ((u >> 16) & 1u);   // round-to-nearest-even
    return (unsigned short)(u >> 16);
}
__device__ __forceinline__ float bf2f(unsigned short u) {
    return __uint_as_float(((unsigned int)u) << 16);
}

struct us8 { unsigned short v[8]; };

// ------------------------------------------------------------------
__global__ void count_k(const int* __restrict__ idx, int* __restrict__ counts, int n) {
    int i = blockIdx.x * blockDim.x + threadIdx.x;
    if (i < n) atomicAdd(&counts[idx[i]], 1);
}

// ---- 3-phase parallel exclusive scan for edge CSR rowptr ----
__global__ void blk_sum_k(const int* __restrict__ counts, int n, int* __restrict__ bsum) {
    __shared__ int buf[256];
    int t = threadIdx.x, i = blockIdx.x * 256 + t;
    buf[t] = (i < n) ? counts[i] : 0;
    __syncthreads();
    for (int off = 128; off > 0; off >>= 1) {
        if (t < off) buf[t] += buf[t + off];
        __syncthreads();
    }
    if (t == 0) bsum[blockIdx.x] = buf[0];
}

__global__ void scan_small_k(const int* __restrict__ bsum, int nb, int* __restrict__ boff) {
    __shared__ int buf[256];
    int t = threadIdx.x;
    int v = (t < nb) ? bsum[t] : 0;
    buf[t] = v;
    __syncthreads();
    for (int off = 1; off < 256; off <<= 1) {
        int u = (t >= off) ? buf[t - off] : 0;
        __syncthreads();
        buf[t] += u;
        __syncthreads();
    }
    if (t < nb) boff[t] = buf[t] - v;
}

__global__ void rowptr_fill_k(const int* __restrict__ counts, const int* __restrict__ boff,
                              int n, int* __restrict__ rowptr, int total) {
    __shared__ int buf[256];
    int t = threadIdx.x, i = blockIdx.x * 256 + t;
    int v = (i < n) ? counts[i] : 0;
    buf[t] = v;
    __syncthreads();
    for (int off = 1; off < 256; off <<= 1) {
        int u = (t >= off) ? buf[t - off] : 0;
        __syncthreads();
        buf[t] += u;
        __syncthreads();
    }
    if (i < n) rowptr[i] = boff[blockIdx.x] + buf[t] - v;
    if (i == 0) rowptr[n] = total;
}

// rowptr for SORTED arrays: rowptr[i] = lower_bound(arr, i), i in [0, m]
__global__ void lb_rowptr_k(const int* __restrict__ arr, int n, int* __restrict__ rowptr, int m) {
    int i = blockIdx.x * blockDim.x + threadIdx.x;
    if (i > m) return;
    int lo = 0, hi = n;
    while (lo < hi) {
        int mid = (lo + hi) >> 1;
        if (arr[mid] < i) lo = mid + 1; else hi = mid;
    }
    rowptr[i] = lo;
}

__global__ void fill_csr_k(const int* __restrict__ esrc, const int* __restrict__ edst,
                           const int* __restrict__ rowptr, int* __restrict__ cursor,
                           int* __restrict__ outi, int n) {
    int e = blockIdx.x * blockDim.x + threadIdx.x;
    if (e < n) {
        int d = edst[e];
        int pos = atomicAdd(&cursor[d], 1);
        outi[rowptr[d] + pos] = esrc[e];
    }
}

// ------------------------------------------------------------------
__global__ void xbf_k(const float* __restrict__ x, unsigned short* __restrict__ xb, int n) {
    int i = blockIdx.x * blockDim.x + threadIdx.x;
    if (i < n) xb[i] = f2bf(x[i]);
}

__global__ void wt_k(const float* __restrict__ Ws, const float* __restrict__ Wn,
                     unsigned short* __restrict__ Wt, int Kin) {
    int i = blockIdx.x * blockDim.x + threadIdx.x;
    int K = 2 * Kin;
    if (i < HD * K) {
        int c = i / K, k = i - c * K;
        Wt[i] = f2bf((k < Kin) ? Ws[k * HD + c] : Wn[(k - Kin) * HD + c]);
    }
}

__global__ void wd1t_k(const float* __restrict__ Wd1, unsigned short* __restrict__ Wd1t) {
    int i = blockIdx.x * blockDim.x + threadIdx.x;
    if (i < 384 * 384) {
        int n = i / 384, k = i - n * 384;
        Wd1t[n * 384 + k] = f2bf(Wd1[k * 384 + n]);
    }
}

// ------------------------------------------------------------------
// mean-aggregation, bf16: 1 wave per node; wave split into 64/LPR sub-groups,
// each sub-group (LPR lanes x ushort8 = full row) handles one edge -> EPW
// concurrent latency chains per wave. Next-src prefetch overlaps index load.
template <int KIN>
__launch_bounds__(256)
__global__ void agg2_k(const unsigned short* __restrict__ h, const int* __restrict__ rowptr,
                       const int* __restrict__ csr_src, unsigned short* __restrict__ aggout) {
    constexpr int LPR = KIN >> 3;      // lanes per row (ushort8 each)
    constexpr int EPW = 64 / LPR;      // edges in flight per wave
    int node = blockIdx.x * 4 + (threadIdx.x >> 6);
    int lane = threadIdx.x & 63;
    int sub = lane / LPR;
    int fl = lane % LPR;
    if (node >= NN) return;
    int s = rowptr[node], e = rowptr[node + 1];
    float acc[8] = {};
    int i = s + sub;
    int src_next = (i < e) ? csr_src[i] : 0;
    for (; i < e; i += EPW) {
        int src = src_next;
        int in = i + EPW;
        if (in < e) src_next = csr_src[in];
        us8 v = *(const us8*)&h[(size_t)src * KIN + fl * 8];
#pragma unroll
        for (int j = 0; j < 8; ++j) acc[j] += bf2f(v.v[j]);
    }
#pragma unroll
    for (int m = LPR; m < 64; m <<= 1)
#pragma unroll
        for (int j = 0; j < 8; ++j) acc[j] += __shfl_xor(acc[j], m);
    if (sub == 0) {
        float d = fmaxf((float)(e - s), 1.f);
        us8 o;
#pragma unroll
        for (int j = 0; j < 8; ++j) o.v[j] = f2bf(acc[j] / d);
        *(us8*)&aggout[(size_t)node * KIN + fl * 8] = o;
    }
}

// ------------------------------------------------------------------
// dst segment-sum -> dstf[P][128] bf16.  Wave per p, 4 sub-groups of 16 lanes,
// 4 edges in flight; avg seg len = 2 so most waves do 1 iteration.
__launch_bounds__(256)
__global__ void dst_sum_k(const unsigned short* __restrict__ feats,
                          const int* __restrict__ t_idx, const int* __restrict__ dst_nodes,
                          const int* __restrict__ dst_rowptr, unsigned short* __restrict__ dstf) {
    int p = blockIdx.x * 4 + (threadIdx.x >> 6);
    int lane = threadIdx.x & 63;
    int sub = lane >> 4;
    int fl = lane & 15;
    if (p >= PP) return;
    long t = t_idx[p];
    const unsigned short* base = feats + t * (long)NN * HD;
    int s = dst_rowptr[p], e = dst_rowptr[p + 1];
    float acc[8] = {};
    int i = s + sub;
    int nd_next = (i < e) ? dst_nodes[i] : 0;
    for (; i < e; i += 4) {
        int nd = nd_next;
        int in = i + 4;
        if (in < e) nd_next = dst_nodes[in];
        us8 v = *(const us8*)&base[(size_t)nd * HD + fl * 8];
#pragma unroll
        for (int j = 0; j < 8; ++j) acc[j] += bf2f(v.v[j]);
    }
#pragma unroll
    for (int m = 16; m < 64; m <<= 1)
#pragma unroll
        for (int j = 0; j < 8; ++j) acc[j] += __shfl_xor(acc[j], m);
    if (sub == 0) {
        us8 o;
#pragma unroll
        for (int j = 0; j < 8; ++j) o.v[j] = f2bf(acc[j]);
        *(us8*)&dstf[(size_t)p * HD + fl * 8] = o;
    }
}

// ------------------------------------------------------------------
// h_out = relu([hin | agg] @ Wt^T + b), bf16 MFMA, no LDS.
__launch_bounds__(256)
__global__ void mp_mfma_k(const unsigned short* __restrict__ hin,
                          const unsigned short* __restrict__ aggin,
                          const unsigned short* __restrict__ Wt,
                          const float* __restrict__ bias,
                          unsigned short* __restrict__ hout, int Kin) {
    int tid = threadIdx.x;
    int lane = tid & 63, w = tid >> 6;
    int cc = lane & 15, g = lane >> 4;
    int K = 2 * Kin;
    int rowA = blockIdx.x * 64 + w * 16 + cc;
    bool rowok = rowA < NN;
    const unsigned short* hrow = hin + (size_t)rowA * Kin;
    const unsigned short* arow = aggin + (size_t)rowA * Kin;

    f32x4 acc[8];
#pragma unroll
    for (int t = 0; t < 8; ++t) acc[t] = (f32x4){0.f, 0.f, 0.f, 0.f};

    for (int k0 = 0; k0 < K; k0 += 32) {
        int k = k0 + g * 8;
        short8 a = {0, 0, 0, 0, 0, 0, 0, 0};
        if (rowok)
            a = *(const short8*)((k < Kin) ? (hrow + k) : (arow + (k - Kin)));
#pragma unroll
        for (int t = 0; t < 8; ++t) {
            short8 b = *(const short8*)&Wt[(size_t)(t * 16 + cc) * K + k];
            acc[t] = __builtin_amdgcn_mfma_f32_16x16x32_bf16(a, b, acc[t], 0, 0, 0);
        }
    }
#pragma unroll
    for (int t = 0; t < 8; ++t) {
        int col = t * 16 + cc;
        float b1 = bias[col];
#pragma unroll
        for (int r = 0; r < 4; ++r) {
            int grow = blockIdx.x * 64 + w * 16 + g * 4 + r;
            if (grow < NN)
                hout[(size_t)grow * HD + col] = f2bf(fmaxf(acc[t][r] + b1, 0.f));
        }
    }
}

// ------------------------------------------------------------------
// fused decoder: 3 uniform row gathers (place/src/dstf) -> LDS -> MFMA vs Wd1t
// -> relu -> Wd2 -> log_softmax
__launch_bounds__(256)
__global__ void dec_gemm_k(const unsigned short* __restrict__ feats,
                           const unsigned short* __restrict__ dstf,
                           const int* __restrict__ place_idx, const int* __restrict__ src_idx,
                           const int* __restrict__ t_idx,
                           const unsigned short* __restrict__ Wd1t,
                           const float* __restrict__ bd1, const float* __restrict__ Wd2,
                           const float* __restrict__ bd2, float* __restrict__ logprob) {
    __shared__ unsigned short catL[64 * 392];
    __shared__ float lpart[4][64][2];
    int tid = threadIdx.x;
    int p0 = blockIdx.x * 64;

    // ---- gather: 3 sections x 64 rows x 16 strips of ushort8; 12 independent
    // loads per thread -> high MLP even at low occupancy ----
#pragma unroll
    for (int it = 0; it < 4; ++it) {
        int l = it * 256 + tid;
        int r = l >> 4, st = (l & 15) * 8;
        int p = p0 + r;
        us8 v = {};
        if (p < PP) {
            long t = t_idx[p];
            v = *(const us8*)(feats + ((t * NN + place_idx[p]) * (long)HD + st));
        }
        *(us8*)&catL[r * 392 + st] = v;
    }
#pragma unroll
    for (int it = 0; it < 4; ++it) {
        int l = it * 256 + tid;
        int r = l >> 4, st = (l & 15) * 8;
        int p = p0 + r;
        us8 v = {};
        if (p < PP) {
            long t = t_idx[p];
            v = *(const us8*)(feats + ((t * NN + src_idx[p]) * (long)HD + st));
        }
        *(us8*)&catL[r * 392 + 128 + st] = v;
    }
#pragma unroll
    for (int it = 0; it < 4; ++it) {
        int l = it * 256 + tid;
        int r = l >> 4, st = (l & 15) * 8;
        int p = p0 + r;
        us8 v = {};
        if (p < PP) v = *(const us8*)(dstf + ((size_t)p * HD + st));
        *(us8*)&catL[r * 392 + 256 + st] = v;
    }
    __syncthreads();

    // ---- MFMA GEMM: wave w owns cols w*96..+95 (6 n-tiles), all 64 rows ----
    int lane = tid & 63;
    int w = tid >> 6;
    int cc = lane & 15;
    int g = lane >> 4;
    f32x4 acc[4][6];
#pragma unroll
    for (int s = 0; s < 4; ++s)
#pragma unroll
        for (int t = 0; t < 6; ++t) acc[s][t] = (f32x4){0.f, 0.f, 0.f, 0.f};

    const unsigned short* bbase = Wd1t + ((long)(w * 96 + cc) * 384 + g * 8);

    for (int k0 = 0; k0 < 384; k0 += 32) {
        short8 a[4];
#pragma unroll
        for (int s = 0; s < 4; ++s)
            a[s] = *(const short8*)&catL[(s * 16 + cc) * 392 + k0 + g * 8];
#pragma unroll
        for (int t = 0; t < 6; ++t) {
            short8 b = *(const short8*)(bbase + (long)t * 16 * 384 + k0);
#pragma unroll
            for (int s = 0; s < 4; ++s)
                acc[s][t] = __builtin_amdgcn_mfma_f32_16x16x32_bf16(a[s], b, acc[s][t], 0, 0, 0);
        }
    }

    // ---- epilogue: bias + relu + Wd2, reduce over cols ----
    float part[4][4][2] = {};
#pragma unroll
    for (int t = 0; t < 6; ++t) {
        int col = w * 96 + t * 16 + cc;
        float b1 = bd1[col];
        float w0 = Wd2[col * 2 + 0], w1 = Wd2[col * 2 + 1];
#pragma unroll
        for (int s = 0; s < 4; ++s)
#pragma unroll
            for (int r = 0; r < 4; ++r) {
                float h = fmaxf(acc[s][t][r] + b1, 0.f);
                part[s][r][0] += h * w0;
                part[s][r][1] += h * w1;
            }
    }
#pragma unroll
    for (int m = 1; m < 16; m <<= 1) {
#pragma unroll
        for (int s = 0; s < 4; ++s)
#pragma unroll
            for (int r = 0; r < 4; ++r) {
                part[s][r][0] += __shfl_xor(part[s][r][0], m);
                part[s][r][1] += __shfl_xor(part[s][r][1], m);
            }
    }
    if (cc == 0) {
#pragma unroll
        for (int s = 0; s < 4; ++s)
#pragma unroll
            for (int r = 0; r < 4; ++r) {
                int row = s * 16 + g * 4 + r;
                lpart[w][row][0] = part[s][r][0];
                lpart[w][row][1] = part[s][r][1];
            }
    }
    __syncthreads();
    if (tid < 64) {
        int p = p0 + tid;
        if (p < PP) {
            float l0 = lpart[0][tid][0] + lpart[1][tid][0] + lpart[2][tid][0] + lpart[3][tid][0] + bd2[0];
            float l1 = lpart[0][tid][1] + lpart[1][tid][1] + lpart[2][tid][1] + lpart[3][tid][1] + bd2[1];
            float m = fmaxf(l0, l1);
            float lse = m + logf(expf(l0 - m) + expf(l1 - m));
            logprob[p * 2 + 0] = l0 - lse;
            logprob[p * 2 + 1] = l1 - lse;
        }
    }
}

// ------------------------------------------------------------------
__global__ void group_sum_k(const float* __restrict__ logprob, const int* __restrict__ group_id,
                            float* __restrict__ group_sums) {
    int p = blockIdx.x * blockDim.x + threadIdx.x;
    if (p >= PP) return;
    int g = group_id[p];
    atomicAdd(&group_sums[g * 2 + 0], logprob[p * 2 + 0]);
    atomicAdd(&group_sums[g * 2 + 1], logprob[p * 2 + 1]);
}

__global__ void within_k(const float* __restrict__ group_sums, const int* __restrict__ var_rowptr,
                         float* __restrict__ within) {
    int v = blockIdx.x * blockDim.x + threadIdx.x;
    if (v >= VV) return;
    int gs = var_rowptr[v], ge = var_rowptr[v + 1];
    float r0 = 0.f, r1 = 0.f;
    for (int g = gs; g < ge; ++g) {
        r0 += group_sums[2 * g + 0];
        r1 += group_sums[2 * g + 1];
        within[2 * g + 0] = r0;
        within[2 * g + 1] = r1;
    }
}

__global__ void total_k(const float* __restrict__ counts, float* __restrict__ total, int n) {
    __shared__ float buf[256];
    float s = 0.f;
    for (int i = threadIdx.x; i < n; i += 256) s += counts[i];
    buf[threadIdx.x] = s;
    __syncthreads();
    for (int off = 128; off > 0; off >>= 1) {
        if (threadIdx.x < off) buf[threadIdx.x] += buf[threadIdx.x + off];
        __syncthreads();
    }
    if (threadIdx.x == 0) total[0] = buf[0];
}

__global__ void final_k(const float* __restrict__ logprob, const float* __restrict__ within,
                        const int* __restrict__ group_id, const int* __restrict__ vog,
                        const float* __restrict__ counts, const float* __restrict__ total,
                        const int* __restrict__ place_idx, float* __restrict__ outp) {
    int p = blockIdx.x * blockDim.x + threadIdx.x;
    if (p >= PP) return;
    int g = group_id[p];
    int v = vog[g];
    float lc = logf(counts[v]) - logf(total[0]);
    int node = place_idx[p];
    atomicAdd(&outp[node * 2 + 0], logprob[p * 2 + 0] + within[g * 2 + 0] + lc);
    atomicAdd(&outp[node * 2 + 1], logprob[p * 2 + 1] + within[g * 2 + 1] + lc);
}

// ------------------------------------------------------------------
extern "C" void kernel_launch(void* const* d_in, const int* in_sizes, int n_in,
                              void* d_out, int out_size, void* d_ws, size_t ws_size,
                              hipStream_t stream) {
    const float* x          = (const float*)d_in[0];
    const float* W_enc_self = (const float*)d_in[1];
    const float* W_enc_nei  = (const float*)d_in[2];
    const float* b_enc      = (const float*)d_in[3];
    const float* W2_self    = (const float*)d_in[4];
    const float* W2_nei     = (const float*)d_in[5];
    const float* b2         = (const float*)d_in[6];
    const float* Wd1        = (const float*)d_in[7];
    const float* bd1        = (const float*)d_in[8];
    const float* Wd2        = (const float*)d_in[9];
    const float* bd2        = (const float*)d_in[10];
    const float* counts     = (const float*)d_in[11];
    const int* edge_src     = (const int*)d_in[12];
    const int* edge_dst     = (const int*)d_in[13];
    const int* place_idx    = (const int*)d_in[14];
    const int* src_idx      = (const int*)d_in[15];
    const int* t_idx        = (const int*)d_in[16];
    const int* dst_nodes    = (const int*)d_in[17];
    const int* dst_seg      = (const int*)d_in[18];
    const int* group_id     = (const int*)d_in[19];
    const int* variant_of_group = (const int*)d_in[20];
    float* outp = (float*)d_out;

    const int NB = (NN + 255) / 256;   // 196 scan blocks

    // ---- workspace layout ----
    unsigned short* feats = (unsigned short*)d_ws;              // 9*N*H bf16
    unsigned short* aggb  = feats + (size_t)(TT + 1) * NN * HD; // N*H
    unsigned short* xb    = aggb + (size_t)NN * HD;             // N*FIN
    unsigned short* dstf  = xb + (size_t)NN * FINN;             // P*H bf16
    unsigned short* wenc_t = dstf + (size_t)PP * HD;            // 128*128
    unsigned short* w2_t   = wenc_t + HD * 2 * FINN;            // 128*256
    unsigned short* wd1t   = w2_t + HD * 2 * HD;                // 384*384
    int* zr = (int*)(wd1t + 384 * 384);                         // zero-region start
    int* csr_counts   = zr;                                     // N
    int* csr_cursor   = csr_counts + NN;                        // N
    float* group_sums = (float*)(csr_cursor + NN);              // 2G
    size_t zero_words = (size_t)NN + NN + 2 * GG;
    int* bsum       = (int*)(group_sums + 2 * GG);              // 256
    int* boff       = bsum + 256;                               // 256
    int* csr_rowptr = boff + 256;                               // N+1
    int* dst_rowptr = csr_rowptr + (NN + 1);                    // P+1
    int* var_rowptr = dst_rowptr + (PP + 1);                    // V+1
    int* csr_src    = var_rowptr + (VV + 1);                    // E
    float* logprob  = (float*)(csr_src + EE);                   // 2P
    float* within   = logprob + 2 * PP;                         // 2G
    float* total_counts = within + 2 * GG;                      // 1

    hipMemsetAsync(zr, 0, zero_words * 4, stream);
    hipMemsetAsync(d_out, 0, (size_t)out_size * sizeof(float), stream);

    // ---- prep: conversions, transposes, CSRs ----
    xbf_k<<<(NN * FINN + 255) / 256, 256, 0, stream>>>(x, xb, NN * FINN);
    wt_k<<<(HD * 2 * FINN + 255) / 256, 256, 0, stream>>>(W_enc_self, W_enc_nei, wenc_t, FINN);
    wt_k<<<(HD * 2 * HD + 255) / 256, 256, 0, stream>>>(W2_self, W2_nei, w2_t, HD);
    wd1t_k<<<(384 * 384 + 255) / 256, 256, 0, stream>>>(Wd1, wd1t);

    count_k<<<(EE + 255) / 256, 256, 0, stream>>>(edge_dst, csr_counts, EE);
    blk_sum_k<<<NB, 256, 0, stream>>>(csr_counts, NN, bsum);
    scan_small_k<<<1, 256, 0, stream>>>(bsum, NB, boff);
    rowptr_fill_k<<<NB, 256, 0, stream>>>(csr_counts, boff, NN, csr_rowptr, EE);
    fill_csr_k<<<(EE + 255) / 256, 256, 0, stream>>>(edge_src, edge_dst, csr_rowptr,
                                                     csr_cursor, csr_src, EE);
    lb_rowptr_k<<<(PP + 256) / 256, 256, 0, stream>>>(dst_seg, DD, dst_rowptr, PP);
    lb_rowptr_k<<<(VV + 256) / 256, 256, 0, stream>>>(variant_of_group, GG, var_rowptr, VV);

    // ---- 9 message-passing rounds (bf16) ----
    for (int r = 0; r <= TT; ++r) {
        const unsigned short* hin = (r == 0) ? xb : feats + (size_t)(r - 1) * NN * HD;
        unsigned short* hout = feats + (size_t)r * NN * HD;
        if (r == 0) {
            agg2_k<FINN><<<(NN + 3) / 4, 256, 0, stream>>>(hin, csr_rowptr, csr_src, aggb);
            mp_mfma_k<<<(NN + 63) / 64, 256, 0, stream>>>(hin, aggb, wenc_t, b_enc, hout, FINN);
        } else {
            agg2_k<HD><<<(NN + 3) / 4, 256, 0, stream>>>(hin, csr_rowptr, csr_src, aggb);
            mp_mfma_k<<<(NN + 63) / 64, 256, 0, stream>>>(hin, aggb, w2_t, b2, hout, HD);
        }
    }

    // ---- dst segment-sum, then fused MFMA decoder ----
    dst_sum_k<<<(PP + 3) / 4, 256, 0, stream>>>(feats, t_idx, dst_nodes, dst_rowptr, dstf);
    dec_gemm_k<<<(PP + 63) / 64, 256, 0, stream>>>(feats, dstf, place_idx, src_idx, t_idx,
                                                   wd1t, bd1, Wd2, bd2, logprob);

    // ---- group / variant running-sum machinery ----
    group_sum_k<<<(PP + 255) / 256, 256, 0, stream>>>(logprob, group_id, group_sums);
    within_k<<<(VV + 255) / 256, 256, 0, stream>>>(group_sums, var_rowptr, within);
    total_k<<<1, 256, 0, stream>>>(counts, total_counts, VV);
    final_k<<<(PP + 255) / 256, 256, 0, stream>>>(logprob, within, group_id, variant_of_group,
                                                  counts, total_counts, place_idx, outp);
}